// Round 10
// baseline (323.648 us; speedup 1.0000x reference)
//
#include <hip/hip_runtime.h>
#include <stdint.h>
#include <stddef.h>

#define TOK    16384     // B*S
#define DDIM   1024
#define NEXP   8
#define BMT    128       // expert gemm row tile (padding quantum)
#define RB_MAX 136       // ceil((TOK + NEXP*BMT)/BMT) upper bound
#define MARGIN 2.5e-2f   // single-bf16 logit ambiguity margin (~11 sigma of pairwise err)
#define BK     64        // K-tile

typedef __bf16 bf16x8 __attribute__((ext_vector_type(8)));
typedef float  f32x4  __attribute__((ext_vector_type(4)));
typedef unsigned short u16x8 __attribute__((ext_vector_type(8)));

__device__ __forceinline__ unsigned short f2bf(float f) {
    unsigned int u = __float_as_uint(f);
    u += 0x7fff + ((u >> 16) & 1);          // round-to-nearest-even
    return (unsigned short)(u >> 16);
}

__device__ __forceinline__ void gload_lds16(const void* g, void* l) {
    __builtin_amdgcn_global_load_lds(
        (const __attribute__((address_space(1))) unsigned int*)g,
        (__attribute__((address_space(3))) unsigned int*)l, 16, 0, 0);
}

// padded segment starts from cnt (redundant per-thread register compute)
__device__ __forceinline__ void seg_starts(const int* __restrict__ cnt, int* st) {
    int total = 0;
#pragma unroll
    for (int e = 0; e < NEXP; e++) {
        st[e] = total;
        total += ((cnt[e] + BMT - 1) / BMT) * BMT;
    }
    st[NEXP] = total;
}

// ---------------------------------------------------------------------------
// x fp32 -> xbf bf16 (single rounding). Block 0 performs control-buffer init.
// ---------------------------------------------------------------------------
__global__ __launch_bounds__(256) void cvt_x_init(
    const float* __restrict__ x, unsigned short* __restrict__ xbf,
    int* __restrict__ cnt, int* __restrict__ cursor,
    int* __restrict__ row_of_slot)
{
    if (blockIdx.x == 0) {
        for (int i = threadIdx.x; i < RB_MAX * BMT; i += 256) row_of_slot[i] = -1;
        if (threadIdx.x < NEXP) { cnt[threadIdx.x] = 0; cursor[threadIdx.x] = 0; }
    }
    const size_t t = ((size_t)blockIdx.x * 256 + threadIdx.x) * 8;
    const float4 v0 = *(const float4*)(x + t);
    const float4 v1 = *(const float4*)(x + t + 4);
    const float vv[8] = {v0.x, v0.y, v0.z, v0.w, v1.x, v1.y, v1.z, v1.w};
    u16x8 hh;
#pragma unroll
    for (int j = 0; j < 8; j++) hh[j] = f2bf(vv[j]);
    *(u16x8*)(xbf + t) = hh;
}

// ---------------------------------------------------------------------------
// We[e][k][n] fp32 -> WeT[e][n][k] bf16
// ---------------------------------------------------------------------------
__global__ __launch_bounds__(256) void transpose_mat(
    const float* __restrict__ src0, unsigned short* __restrict__ dst0)
{
    __shared__ float tile[32][33];
    const int e  = blockIdx.z;
    const int k0 = blockIdx.x * 32;
    const int n0 = blockIdx.y * 32;
    const int tx = threadIdx.x;
    const int ty = threadIdx.y;
    const float* src = src0 + (size_t)e * DDIM * DDIM;
    unsigned short* dst = dst0 + (size_t)e * DDIM * DDIM;
#pragma unroll
    for (int r = 0; r < 4; r++)
        tile[ty + r * 8][tx] = src[(size_t)(k0 + ty + r * 8) * DDIM + n0 + tx];
    __syncthreads();
#pragma unroll
    for (int r = 0; r < 4; r++)
        dst[(size_t)(n0 + ty + r * 8) * DDIM + k0 + tx] = f2bf(tile[tx][ty + r * 8]);
}

// ---------------------------------------------------------------------------
// Wg[k][n] fp32 -> WgT[n][k] bf16 AND WgTf[n][k] fp32 in one pass
// ---------------------------------------------------------------------------
__global__ __launch_bounds__(256) void transpose_wg(
    const float* __restrict__ src, unsigned short* __restrict__ dstb,
    float* __restrict__ dstf)
{
    __shared__ float tile[32][33];
    const int k0 = blockIdx.x * 32;
    const int n0 = blockIdx.y * 32;
    const int tx = threadIdx.x;
    const int ty = threadIdx.y;
#pragma unroll
    for (int r = 0; r < 4; r++)
        tile[ty + r * 8][tx] = src[(size_t)(k0 + ty + r * 8) * DDIM + n0 + tx];
    __syncthreads();
#pragma unroll
    for (int r = 0; r < 4; r++) {
        const float v = tile[tx][ty + r * 8];
        const size_t o = (size_t)(n0 + ty + r * 8) * DDIM + k0 + tx;
        dstb[o] = f2bf(v);
        dstf[o] = v;
    }
}

// ---------------------------------------------------------------------------
// Gating GEMM, round-7 proven structure + chunked XCD swizzle (T1):
// XCD x (= bid&7) gets nb-fastest 16x4 tile chunks -> A panel reused by 4
// consecutive same-XCD blocks, B panels stay L2-resident per XCD.
// grid = 1024 (1-D), 128 rb x 8 nb.
// ---------------------------------------------------------------------------
__global__ __launch_bounds__(256) void gating_mfma(
    const unsigned short* __restrict__ xbf,
    const unsigned short* __restrict__ WgT,
    const float* __restrict__ bg, float* __restrict__ logits)
{
    __shared__ unsigned short Asm[128 * BK];
    __shared__ unsigned short Bsm[128 * BK];
    const int bid = blockIdx.x;
    const int xcd = bid & 7;
    const int seq = bid >> 3;              // 0..127 (per-XCD sequence)
    const int cl  = seq >> 6;              // chunk_local 0..1 (nb half)
    const int w   = seq & 63;              // within 16x4 chunk, nb-fastest
    const int rb  = xcd * 16 + (w >> 2);
    const int nb  = cl * 4 + (w & 3);
    const int tid  = threadIdx.x;
    const int lane = tid & 63;
    const int wave = tid >> 6;
    const int q    = lane >> 4;
    const int m16  = lane & 15;
    const int wrow = (wave & 1) * 64;
    const int wcol = (wave >> 1) * 64;

    const unsigned short* Ag = xbf + (size_t)rb * 128 * DDIM;
    const unsigned short* Bg = WgT + (size_t)nb * 128 * DDIM;

    const unsigned short* pa[4];
    const unsigned short* pb[4];
#pragma unroll
    for (int i = 0; i < 4; i++) {
        const int idx = tid + i * 256;
        const int r = idx >> 3;
        const int c = idx & 7;
        const int g = (c ^ (r & 7)) * 8;
        pa[i] = Ag + (size_t)r * DDIM + g;
        pb[i] = Bg + (size_t)r * DDIM + g;
    }

    f32x4 acc[4][4];
#pragma unroll
    for (int i = 0; i < 4; i++)
#pragma unroll
        for (int j = 0; j < 4; j++) acc[i][j] = (f32x4){0.f, 0.f, 0.f, 0.f};

    for (int k0 = 0; k0 < DDIM; k0 += BK) {
#pragma unroll
        for (int i = 0; i < 4; i++) {
            gload_lds16(pa[i] + k0, &Asm[(tid + i * 256) * 8]);
            gload_lds16(pb[i] + k0, &Bsm[(tid + i * 256) * 8]);
        }
        __syncthreads();
#pragma unroll
        for (int s = 0; s < 2; s++) {
            const int cs = (((s << 2) + q) ^ (m16 & 7)) << 3;
            bf16x8 af[4], bfr[4];
#pragma unroll
            for (int i = 0; i < 4; i++)
                af[i] = *(const bf16x8*)&Asm[(wrow + i * 16 + m16) * BK + cs];
#pragma unroll
            for (int j = 0; j < 4; j++)
                bfr[j] = *(const bf16x8*)&Bsm[(wcol + j * 16 + m16) * BK + cs];
#pragma unroll
            for (int i = 0; i < 4; i++)
#pragma unroll
                for (int j = 0; j < 4; j++)
                    acc[i][j] = __builtin_amdgcn_mfma_f32_16x16x32_bf16(
                        af[i], bfr[j], acc[i][j], 0, 0, 0);
        }
        __syncthreads();
    }

    float bgv[4];
#pragma unroll
    for (int j = 0; j < 4; j++) bgv[j] = bg[nb * 128 + wcol + j * 16 + m16];
#pragma unroll
    for (int i = 0; i < 4; i++)
#pragma unroll
        for (int r = 0; r < 4; r++) {
            const int row = rb * 128 + wrow + i * 16 + q * 4 + r;
#pragma unroll
            for (int j = 0; j < 4; j++) {
                const int col = nb * 128 + wcol + j * 16 + m16;
                logits[(size_t)row * DDIM + col] = acc[i][j][r] + bgv[j];
            }
        }
}

// ---------------------------------------------------------------------------
// Row stats + inline fp64 fixup + block histogram (fused; fixup & histo
// kernels eliminated). One wave per row. Ambiguous rows (top-2 gap<MARGIN)
// rescore candidates in fp64 from x,WgTf inline — per-wave LDS lists, no
// cross-wave sync in the divergent region; unconditional barrier at histo.
// ---------------------------------------------------------------------------
__global__ __launch_bounds__(256) void row_stats(
    const float* __restrict__ logits, const float* __restrict__ x,
    const float* __restrict__ WgTf, const float* __restrict__ bg,
    float* __restrict__ pout, int* __restrict__ eout, int* __restrict__ cnt)
{
    __shared__ int   scnt[4];
    __shared__ int   scol[4][32];
    __shared__ float sval[4][32];
    __shared__ int   hcnt[NEXP];
    const int wv   = threadIdx.x >> 6;
    const int row  = blockIdx.x * 4 + wv;
    const int lane = threadIdx.x & 63;
    if (threadIdx.x < NEXP) hcnt[threadIdx.x] = 0;
    __syncthreads();

    const float* L = logits + (size_t)row * DDIM;
    float vals[16];
#pragma unroll
    for (int i = 0; i < 4; i++)
        *(float4*)&vals[i * 4] = *(const float4*)&L[lane * 16 + i * 4];
    float m = vals[0]; int mi = lane * 16;
#pragma unroll
    for (int i = 1; i < 16; i++)
        if (vals[i] > m) { m = vals[i]; mi = lane * 16 + i; }
    for (int off = 32; off > 0; off >>= 1) {
        float ov = __shfl_down(m, off, 64);
        int   oi = __shfl_down(mi, off, 64);
        if (ov > m || (ov == m && oi < mi)) { m = ov; mi = oi; }
    }
    m  = __shfl(m, 0, 64);
    mi = __shfl(mi, 0, 64);
    float s = 0.f;
    int   c = 0;
#pragma unroll
    for (int i = 0; i < 16; i++) {
        s += expf(vals[i] - m);
        if (vals[i] >= m - MARGIN) c++;
    }
    for (int off = 32; off > 0; off >>= 1) {
        s += __shfl_xor(s, off, 64);
        c += __shfl_xor(c, off, 64);
    }

    int my_e; float my_p;
    if (c > 1) {            // wave-uniform (c reduced across all 64 lanes)
        if (lane == 0) scnt[wv] = 0;
#pragma unroll
        for (int i = 0; i < 16; i++)
            if (vals[i] >= m - MARGIN) {
                int k = atomicAdd(&scnt[wv], 1);
                if (k < 32) { scol[wv][k] = lane * 16 + i; sval[wv][k] = vals[i]; }
            }
        int ncand = scnt[wv]; if (ncand > 32) ncand = 32;
        double bestv = -1e300; int bestc = DDIM; float bestL = 0.f;
        for (int cidx = 0; cidx < ncand; cidx++) {
            const int col = scol[wv][cidx];
            const float* Wcol = WgTf + (size_t)col * DDIM;
            double sd = 0.0;
            for (int k = lane; k < DDIM; k += 64)
                sd += (double)x[(size_t)row * DDIM + k] * (double)Wcol[k];
            for (int off = 32; off > 0; off >>= 1) sd += __shfl_down(sd, off, 64);
            sd = __shfl(sd, 0, 64);
            sd += (double)bg[col];
            if (sd > bestv || (sd == bestv && col < bestc)) {
                bestv = sd; bestc = col; bestL = sval[wv][cidx];
            }
        }
        my_e = bestc & (NEXP - 1);
        my_p = expf(bestL - m) / s;
    } else {
        my_e = mi & (NEXP - 1);
        my_p = 1.0f / s;
    }
    if (lane == 0) {
        pout[row] = my_p;
        eout[row] = my_e;
        atomicAdd(&hcnt[my_e], 1);
    }
    __syncthreads();
    if (threadIdx.x < NEXP && hcnt[threadIdx.x] > 0)
        atomicAdd(&cnt[threadIdx.x], hcnt[threadIdx.x]);
}

// ---------------------------------------------------------------------------
// token -> slot, block-aggregated atomics; segment starts from cnt in-kernel
// ---------------------------------------------------------------------------
__global__ __launch_bounds__(256) void assign_slots(
    const int* __restrict__ eout, const int* __restrict__ cnt,
    int* __restrict__ cursor, int* __restrict__ row_of_slot)
{
    __shared__ int h[NEXP];
    __shared__ int base[NEXP];
    __shared__ int sstart[NEXP];
    const int tid = threadIdx.x;
    if (tid < NEXP) {
        h[tid] = 0;
        int st[NEXP + 1];
        seg_starts(cnt, st);
        sstart[tid] = st[tid];
    }
    __syncthreads();
    const int t = blockIdx.x * 256 + tid;
    int e = 0, lr = 0;
    if (t < TOK) {
        e = eout[t];
        lr = atomicAdd(&h[e], 1);
    }
    __syncthreads();
    if (tid < NEXP && h[tid] > 0)
        base[tid] = atomicAdd(&cursor[tid], h[tid]);
    __syncthreads();
    if (t < TOK)
        row_of_slot[sstart[e] + base[e] + lr] = t;
}

// ---------------------------------------------------------------------------
// Expert GEMM, round-7 structure + chunked XCD swizzle (17x4 chunks,
// nb-fastest). grid = 1088 (1-D), 136 rb x 8 nb. Expert id from cnt.
// ---------------------------------------------------------------------------
__global__ __launch_bounds__(256) void expert_gemm(
    const unsigned short* __restrict__ xbf, const unsigned short* __restrict__ WeT,
    const float* __restrict__ be, const float* __restrict__ p,
    const int* __restrict__ row_of_slot, const int* __restrict__ cnt,
    float* __restrict__ out)
{
    __shared__ unsigned short Asm[128 * BK];
    __shared__ unsigned short Bsm[128 * BK];
    __shared__ int rs[128];
    const int bid = blockIdx.x;
    const int xcd = bid & 7;
    const int seq = bid >> 3;              // 0..135
    const int cl  = seq / 68;
    const int w   = seq % 68;
    const int rb  = xcd * 17 + (w >> 2);
    const int nb  = cl * 4 + (w & 3);

    int st[NEXP + 1];
    seg_starts(cnt, st);
    const int s0 = rb * BMT;
    int e = -1;
#pragma unroll
    for (int ei = 0; ei < NEXP; ei++)
        if (s0 >= st[ei] && s0 < st[ei + 1]) e = ei;
    if (e < 0) return;

    const int tid  = threadIdx.x;
    const int lane = tid & 63;
    const int wave = tid >> 6;
    const int q    = lane >> 4;
    const int m16  = lane & 15;
    const int wrow = (wave & 1) * 64;
    const int wcol = (wave >> 1) * 64;

    if (tid < 128) rs[tid] = row_of_slot[rb * 128 + tid];
    __syncthreads();

    const unsigned short* Bglob = WeT + (size_t)e * DDIM * DDIM + (size_t)nb * 128 * DDIM;

    const unsigned short* pa[4];
    const unsigned short* pb[4];
#pragma unroll
    for (int i = 0; i < 4; i++) {
        const int idx = tid + i * 256;
        const int r = idx >> 3;
        const int c = idx & 7;
        const int g = (c ^ (r & 7)) * 8;
        int tr = rs[r]; if (tr < 0) tr = 0;
        pa[i] = xbf + (size_t)tr * DDIM + g;
        pb[i] = Bglob + (size_t)r * DDIM + g;
    }

    f32x4 acc[4][4];
#pragma unroll
    for (int i = 0; i < 4; i++)
#pragma unroll
        for (int j = 0; j < 4; j++) acc[i][j] = (f32x4){0.f, 0.f, 0.f, 0.f};

    for (int k0 = 0; k0 < DDIM; k0 += BK) {
#pragma unroll
        for (int i = 0; i < 4; i++) {
            gload_lds16(pa[i] + k0, &Asm[(tid + i * 256) * 8]);
            gload_lds16(pb[i] + k0, &Bsm[(tid + i * 256) * 8]);
        }
        __syncthreads();
#pragma unroll
        for (int s = 0; s < 2; s++) {
            const int cs = (((s << 2) + q) ^ (m16 & 7)) << 3;
            bf16x8 af[4], bfr[4];
#pragma unroll
            for (int i = 0; i < 4; i++)
                af[i] = *(const bf16x8*)&Asm[(wrow + i * 16 + m16) * BK + cs];
#pragma unroll
            for (int j = 0; j < 4; j++)
                bfr[j] = *(const bf16x8*)&Bsm[(wcol + j * 16 + m16) * BK + cs];
#pragma unroll
            for (int i = 0; i < 4; i++)
#pragma unroll
                for (int j = 0; j < 4; j++)
                    acc[i][j] = __builtin_amdgcn_mfma_f32_16x16x32_bf16(
                        af[i], bfr[j], acc[i][j], 0, 0, 0);
        }
        __syncthreads();
    }

    float bev[4];
#pragma unroll
    for (int j = 0; j < 4; j++) bev[j] = be[e * DDIM + nb * 128 + wcol + j * 16 + m16];
#pragma unroll
    for (int i = 0; i < 4; i++)
#pragma unroll
        for (int r = 0; r < 4; r++) {
            const int t = rs[wrow + i * 16 + q * 4 + r];
            if (t < 0) continue;
            const float pv = p[t];
#pragma unroll
            for (int j = 0; j < 4; j++) {
                const int n = nb * 128 + wcol + j * 16 + m16;
                float v = acc[i][j][r] + bev[j];
                v = v > 0.f ? v : 0.f;
                out[(size_t)t * DDIM + n] = v * pv;
            }
        }
}

// ---------------------------------------------------------------------------
extern "C" void kernel_launch(void* const* d_in, const int* in_sizes, int n_in,
                              void* d_out, int out_size, void* d_ws, size_t ws_size,
                              hipStream_t stream)
{
    const float* x  = (const float*)d_in[0];
    const float* Wg = (const float*)d_in[1];
    const float* bg = (const float*)d_in[2];
    const float* We = (const float*)d_in[3];
    const float* be = (const float*)d_in[4];
    float* out = (float*)d_out;

    char* ws = (char*)d_ws;
    float* logits = (float*)ws;                 ws += (size_t)TOK * DDIM * 4;
    unsigned short* WeT = (unsigned short*)ws;  ws += (size_t)NEXP * DDIM * DDIM * 2;
    unsigned short* WgT = (unsigned short*)ws;  ws += (size_t)DDIM * DDIM * 2;
    float* WgTf = (float*)ws;                   ws += (size_t)DDIM * DDIM * 4;
    unsigned short* xbf = (unsigned short*)ws;  ws += (size_t)TOK * DDIM * 2;
    float* p = (float*)ws;                      ws += (size_t)TOK * 4;
    int* e_arr = (int*)ws;                      ws += (size_t)TOK * 4;
    int* row_of_slot = (int*)ws;                ws += (size_t)RB_MAX * BMT * 4;
    int* cnt = (int*)ws;                        ws += NEXP * 4;
    int* cursor = (int*)ws;                     ws += NEXP * 4;

    cvt_x_init<<<TOK * DDIM / (256 * 8), 256, 0, stream>>>(
        x, xbf, cnt, cursor, row_of_slot);
    transpose_wg<<<dim3(32, 32), dim3(32, 8), 0, stream>>>(Wg, WgT, WgTf);
    transpose_mat<<<dim3(32, 32, NEXP), dim3(32, 8), 0, stream>>>(We, WeT);
    gating_mfma<<<1024, 256, 0, stream>>>(xbf, WgT, bg, logits);
    row_stats<<<TOK / 4, 256, 0, stream>>>(logits, x, WgTf, bg, p, e_arr, cnt);
    assign_slots<<<TOK / 256, 256, 0, stream>>>(e_arr, cnt, cursor, row_of_slot);
    expert_gemm<<<1088, 256, 0, stream>>>(
        xbf, WeT, be, p, row_of_slot, cnt, out);
}

// Round 11
// 310.726 us; speedup vs baseline: 1.0416x; 1.0416x over previous
//
#include <hip/hip_runtime.h>
#include <stdint.h>
#include <stddef.h>

#define TOK    16384     // B*S
#define DDIM   1024
#define NEXP   8
#define BMT    128       // expert gemm row tile (padding quantum)
#define RB_MAX 136       // ceil((TOK + NEXP*BMT)/BMT) upper bound
#define MARGIN 2.5e-2f   // single-bf16 logit ambiguity margin (~11 sigma of pairwise err)
#define AMBIG_CAP 4096
#define BK     64        // K-tile

typedef __bf16 bf16x8 __attribute__((ext_vector_type(8)));
typedef float  f32x4  __attribute__((ext_vector_type(4)));
typedef unsigned short u16x8 __attribute__((ext_vector_type(8)));

__device__ __forceinline__ unsigned short f2bf(float f) {
    unsigned int u = __float_as_uint(f);
    u += 0x7fff + ((u >> 16) & 1);          // round-to-nearest-even
    return (unsigned short)(u >> 16);
}

__device__ __forceinline__ void gload_lds16(const void* g, void* l) {
    __builtin_amdgcn_global_load_lds(
        (const __attribute__((address_space(1))) unsigned int*)g,
        (__attribute__((address_space(3))) unsigned int*)l, 16, 0, 0);
}

// padded segment starts from cnt (redundant per-thread register compute)
__device__ __forceinline__ void seg_starts(const int* __restrict__ cnt, int* st) {
    int total = 0;
#pragma unroll
    for (int e = 0; e < NEXP; e++) {
        st[e] = total;
        total += ((cnt[e] + BMT - 1) / BMT) * BMT;
    }
    st[NEXP] = total;
}

// ---------------------------------------------------------------------------
// x fp32 -> xbf bf16 (single rounding). Block 0 performs control-buffer init.
// ---------------------------------------------------------------------------
__global__ __launch_bounds__(256) void cvt_x_init(
    const float* __restrict__ x, unsigned short* __restrict__ xbf,
    int* __restrict__ cnt, int* __restrict__ cursor,
    int* __restrict__ n_ambig, int* __restrict__ row_of_slot)
{
    if (blockIdx.x == 0) {
        for (int i = threadIdx.x; i < RB_MAX * BMT; i += 256) row_of_slot[i] = -1;
        if (threadIdx.x < NEXP) { cnt[threadIdx.x] = 0; cursor[threadIdx.x] = 0; }
        if (threadIdx.x == 0) *n_ambig = 0;
    }
    const size_t t = ((size_t)blockIdx.x * 256 + threadIdx.x) * 8;
    const float4 v0 = *(const float4*)(x + t);
    const float4 v1 = *(const float4*)(x + t + 4);
    const float vv[8] = {v0.x, v0.y, v0.z, v0.w, v1.x, v1.y, v1.z, v1.w};
    u16x8 hh;
#pragma unroll
    for (int j = 0; j < 8; j++) hh[j] = f2bf(vv[j]);
    *(u16x8*)(xbf + t) = hh;
}

// ---------------------------------------------------------------------------
// We[e][k][n] fp32 -> WeT[e][n][k] bf16
// ---------------------------------------------------------------------------
__global__ __launch_bounds__(256) void transpose_mat(
    const float* __restrict__ src0, unsigned short* __restrict__ dst0)
{
    __shared__ float tile[32][33];
    const int e  = blockIdx.z;
    const int k0 = blockIdx.x * 32;
    const int n0 = blockIdx.y * 32;
    const int tx = threadIdx.x;
    const int ty = threadIdx.y;
    const float* src = src0 + (size_t)e * DDIM * DDIM;
    unsigned short* dst = dst0 + (size_t)e * DDIM * DDIM;
#pragma unroll
    for (int r = 0; r < 4; r++)
        tile[ty + r * 8][tx] = src[(size_t)(k0 + ty + r * 8) * DDIM + n0 + tx];
    __syncthreads();
#pragma unroll
    for (int r = 0; r < 4; r++)
        dst[(size_t)(n0 + ty + r * 8) * DDIM + k0 + tx] = f2bf(tile[tx][ty + r * 8]);
}

// ---------------------------------------------------------------------------
// Wg[k][n] fp32 -> WgT[n][k] bf16 AND WgTf[n][k] fp32 in one pass
// ---------------------------------------------------------------------------
__global__ __launch_bounds__(256) void transpose_wg(
    const float* __restrict__ src, unsigned short* __restrict__ dstb,
    float* __restrict__ dstf)
{
    __shared__ float tile[32][33];
    const int k0 = blockIdx.x * 32;
    const int n0 = blockIdx.y * 32;
    const int tx = threadIdx.x;
    const int ty = threadIdx.y;
#pragma unroll
    for (int r = 0; r < 4; r++)
        tile[ty + r * 8][tx] = src[(size_t)(k0 + ty + r * 8) * DDIM + n0 + tx];
    __syncthreads();
#pragma unroll
    for (int r = 0; r < 4; r++) {
        const float v = tile[tx][ty + r * 8];
        const size_t o = (size_t)(n0 + ty + r * 8) * DDIM + k0 + tx;
        dstb[o] = f2bf(v);
        dstf[o] = v;
    }
}

// ---------------------------------------------------------------------------
// Gating GEMM, round-7 proven structure + chunked XCD swizzle (T1, proven
// in r10: FETCH halved). grid = 1024 (1-D), 128 rb x 8 nb.
// ---------------------------------------------------------------------------
__global__ __launch_bounds__(256) void gating_mfma(
    const unsigned short* __restrict__ xbf,
    const unsigned short* __restrict__ WgT,
    const float* __restrict__ bg, float* __restrict__ logits)
{
    __shared__ unsigned short Asm[128 * BK];
    __shared__ unsigned short Bsm[128 * BK];
    const int bid = blockIdx.x;
    const int xcd = bid & 7;
    const int seq = bid >> 3;              // 0..127 (per-XCD sequence)
    const int cl  = seq >> 6;              // chunk_local 0..1 (nb half)
    const int w   = seq & 63;              // within 16x4 chunk, nb-fastest
    const int rb  = xcd * 16 + (w >> 2);
    const int nb  = cl * 4 + (w & 3);
    const int tid  = threadIdx.x;
    const int lane = tid & 63;
    const int wave = tid >> 6;
    const int q    = lane >> 4;
    const int m16  = lane & 15;
    const int wrow = (wave & 1) * 64;
    const int wcol = (wave >> 1) * 64;

    const unsigned short* Ag = xbf + (size_t)rb * 128 * DDIM;
    const unsigned short* Bg = WgT + (size_t)nb * 128 * DDIM;

    const unsigned short* pa[4];
    const unsigned short* pb[4];
#pragma unroll
    for (int i = 0; i < 4; i++) {
        const int idx = tid + i * 256;
        const int r = idx >> 3;
        const int c = idx & 7;
        const int g = (c ^ (r & 7)) * 8;
        pa[i] = Ag + (size_t)r * DDIM + g;
        pb[i] = Bg + (size_t)r * DDIM + g;
    }

    f32x4 acc[4][4];
#pragma unroll
    for (int i = 0; i < 4; i++)
#pragma unroll
        for (int j = 0; j < 4; j++) acc[i][j] = (f32x4){0.f, 0.f, 0.f, 0.f};

    for (int k0 = 0; k0 < DDIM; k0 += BK) {
#pragma unroll
        for (int i = 0; i < 4; i++) {
            gload_lds16(pa[i] + k0, &Asm[(tid + i * 256) * 8]);
            gload_lds16(pb[i] + k0, &Bsm[(tid + i * 256) * 8]);
        }
        __syncthreads();
#pragma unroll
        for (int s = 0; s < 2; s++) {
            const int cs = (((s << 2) + q) ^ (m16 & 7)) << 3;
            bf16x8 af[4], bfr[4];
#pragma unroll
            for (int i = 0; i < 4; i++)
                af[i] = *(const bf16x8*)&Asm[(wrow + i * 16 + m16) * BK + cs];
#pragma unroll
            for (int j = 0; j < 4; j++)
                bfr[j] = *(const bf16x8*)&Bsm[(wcol + j * 16 + m16) * BK + cs];
#pragma unroll
            for (int i = 0; i < 4; i++)
#pragma unroll
                for (int j = 0; j < 4; j++)
                    acc[i][j] = __builtin_amdgcn_mfma_f32_16x16x32_bf16(
                        af[i], bfr[j], acc[i][j], 0, 0, 0);
        }
        __syncthreads();
    }

    float bgv[4];
#pragma unroll
    for (int j = 0; j < 4; j++) bgv[j] = bg[nb * 128 + wcol + j * 16 + m16];
#pragma unroll
    for (int i = 0; i < 4; i++)
#pragma unroll
        for (int r = 0; r < 4; r++) {
            const int row = rb * 128 + wrow + i * 16 + q * 4 + r;
#pragma unroll
            for (int j = 0; j < 4; j++) {
                const int col = nb * 128 + wcol + j * 16 + m16;
                logits[(size_t)row * DDIM + col] = acc[i][j][r] + bgv[j];
            }
        }
}

// ---------------------------------------------------------------------------
// Row stats: one wave per row (separate kernel — inlining the divergent
// fp64 rescue regressed 15us in r10: 31% of blocks serialized at the
// closing barrier behind ambiguous waves; dedicated fixup blocks balance).
// ---------------------------------------------------------------------------
__global__ __launch_bounds__(256) void row_stats(
    const float* __restrict__ logits, float* __restrict__ pout,
    int* __restrict__ eout, float* __restrict__ rmax_a, float* __restrict__ s_a,
    int* __restrict__ ambig, int* __restrict__ n_ambig)
{
    const int row  = blockIdx.x * 4 + (threadIdx.x >> 6);
    const int lane = threadIdx.x & 63;
    const float* L = logits + (size_t)row * DDIM;
    float vals[16];
#pragma unroll
    for (int i = 0; i < 4; i++)
        *(float4*)&vals[i * 4] = *(const float4*)&L[lane * 16 + i * 4];
    float m = vals[0]; int mi = lane * 16;
#pragma unroll
    for (int i = 1; i < 16; i++)
        if (vals[i] > m) { m = vals[i]; mi = lane * 16 + i; }
    for (int off = 32; off > 0; off >>= 1) {
        float ov = __shfl_down(m, off, 64);
        int   oi = __shfl_down(mi, off, 64);
        if (ov > m || (ov == m && oi < mi)) { m = ov; mi = oi; }
    }
    m  = __shfl(m, 0, 64);
    mi = __shfl(mi, 0, 64);
    float s = 0.f;
    int   c = 0;
#pragma unroll
    for (int i = 0; i < 16; i++) {
        s += expf(vals[i] - m);
        if (vals[i] >= m - MARGIN) c++;
    }
    for (int off = 32; off > 0; off >>= 1) {
        s += __shfl_xor(s, off, 64);
        c += __shfl_xor(c, off, 64);
    }
    if (lane == 0) {
        pout[row] = 1.0f / s;
        eout[row] = mi & (NEXP - 1);
        rmax_a[row] = m;
        s_a[row] = s;
        if (c > 1) {
            int k = atomicAdd(n_ambig, 1);
            if (k < AMBIG_CAP) ambig[k] = row;
        }
    }
}

// ---------------------------------------------------------------------------
// Fix-up: for ambiguous rows, fp64 re-score candidate columns from fp32 x
// and the fp32 transpose WgTf (coalesced row reads). Commit exact argmax.
// ---------------------------------------------------------------------------
__global__ __launch_bounds__(64) void fixup(
    const float* __restrict__ logits, const float* __restrict__ x,
    const float* __restrict__ WgTf, const float* __restrict__ bg,
    const float* __restrict__ rmax_a, const float* __restrict__ s_a,
    const int* __restrict__ ambig, const int* __restrict__ n_ambig,
    int* __restrict__ eout, float* __restrict__ pout)
{
    int n = *n_ambig; if (n > AMBIG_CAP) n = AMBIG_CAP;
    if ((int)blockIdx.x >= n) return;
    const int row  = ambig[blockIdx.x];
    const int lane = threadIdx.x;
    const float rmax = rmax_a[row];
    const float* L = logits + (size_t)row * DDIM;
    __shared__ int scnt;
    __shared__ int scol[32];
    if (lane == 0) scnt = 0;
    __syncthreads();
    for (int j = lane; j < DDIM; j += 64)
        if (L[j] >= rmax - MARGIN) {
            int k = atomicAdd(&scnt, 1);
            if (k < 32) scol[k] = j;
        }
    __syncthreads();
    int ncand = scnt < 32 ? scnt : 32;
    double bestv = -1e300; int bestc = DDIM;
    for (int cidx = 0; cidx < ncand; cidx++) {
        const int col = scol[cidx];
        const float* Wcol = WgTf + (size_t)col * DDIM;
        double s = 0.0;
        for (int k = lane; k < DDIM; k += 64)
            s += (double)x[(size_t)row * DDIM + k] * (double)Wcol[k];
        for (int off = 32; off > 0; off >>= 1) s += __shfl_down(s, off, 64);
        s = __shfl(s, 0, 64);
        s += (double)bg[col];
        if (s > bestv || (s == bestv && col < bestc)) { bestv = s; bestc = col; }
    }
    if (lane == 0) {
        eout[row] = bestc & (NEXP - 1);
        pout[row] = expf(L[bestc] - rmax) / s_a[row];
    }
}

// ---------------------------------------------------------------------------
// Expert histogram (after fixup so counts are final)
// ---------------------------------------------------------------------------
__global__ __launch_bounds__(256) void histo(const int* __restrict__ eout,
                                             int* __restrict__ cnt)
{
    __shared__ int h[NEXP];
    if (threadIdx.x < NEXP) h[threadIdx.x] = 0;
    __syncthreads();
    const int t = blockIdx.x * 256 + threadIdx.x;
    if (t < TOK) atomicAdd(&h[eout[t]], 1);
    __syncthreads();
    if (threadIdx.x < NEXP) atomicAdd(&cnt[threadIdx.x], h[threadIdx.x]);
}

// ---------------------------------------------------------------------------
// token -> slot, block-aggregated atomics; segment starts from cnt in-kernel
// ---------------------------------------------------------------------------
__global__ __launch_bounds__(256) void assign_slots(
    const int* __restrict__ eout, const int* __restrict__ cnt,
    int* __restrict__ cursor, int* __restrict__ row_of_slot)
{
    __shared__ int h[NEXP];
    __shared__ int base[NEXP];
    __shared__ int sstart[NEXP];
    const int tid = threadIdx.x;
    if (tid < NEXP) {
        h[tid] = 0;
        int st[NEXP + 1];
        seg_starts(cnt, st);
        sstart[tid] = st[tid];
    }
    __syncthreads();
    const int t = blockIdx.x * 256 + tid;
    int e = 0, lr = 0;
    if (t < TOK) {
        e = eout[t];
        lr = atomicAdd(&h[e], 1);
    }
    __syncthreads();
    if (tid < NEXP && h[tid] > 0)
        base[tid] = atomicAdd(&cursor[tid], h[tid]);
    __syncthreads();
    if (t < TOK)
        row_of_slot[sstart[e] + base[e] + lr] = t;
}

// ---------------------------------------------------------------------------
// Expert GEMM, round-7 structure + chunked XCD swizzle (17x4 chunks,
// nb-fastest; proven r10: FETCH 102->54MB). grid = 1088 (1-D).
// ---------------------------------------------------------------------------
__global__ __launch_bounds__(256) void expert_gemm(
    const unsigned short* __restrict__ xbf, const unsigned short* __restrict__ WeT,
    const float* __restrict__ be, const float* __restrict__ p,
    const int* __restrict__ row_of_slot, const int* __restrict__ cnt,
    float* __restrict__ out)
{
    __shared__ unsigned short Asm[128 * BK];
    __shared__ unsigned short Bsm[128 * BK];
    __shared__ int rs[128];
    const int bid = blockIdx.x;
    const int xcd = bid & 7;
    const int seq = bid >> 3;              // 0..135
    const int cl  = seq / 68;
    const int w   = seq % 68;
    const int rb  = xcd * 17 + (w >> 2);
    const int nb  = cl * 4 + (w & 3);

    int st[NEXP + 1];
    seg_starts(cnt, st);
    const int s0 = rb * BMT;
    int e = -1;
#pragma unroll
    for (int ei = 0; ei < NEXP; ei++)
        if (s0 >= st[ei] && s0 < st[ei + 1]) e = ei;
    if (e < 0) return;

    const int tid  = threadIdx.x;
    const int lane = tid & 63;
    const int wave = tid >> 6;
    const int q    = lane >> 4;
    const int m16  = lane & 15;
    const int wrow = (wave & 1) * 64;
    const int wcol = (wave >> 1) * 64;

    if (tid < 128) rs[tid] = row_of_slot[rb * 128 + tid];
    __syncthreads();

    const unsigned short* Bglob = WeT + (size_t)e * DDIM * DDIM + (size_t)nb * 128 * DDIM;

    const unsigned short* pa[4];
    const unsigned short* pb[4];
#pragma unroll
    for (int i = 0; i < 4; i++) {
        const int idx = tid + i * 256;
        const int r = idx >> 3;
        const int c = idx & 7;
        const int g = (c ^ (r & 7)) * 8;
        int tr = rs[r]; if (tr < 0) tr = 0;
        pa[i] = xbf + (size_t)tr * DDIM + g;
        pb[i] = Bglob + (size_t)r * DDIM + g;
    }

    f32x4 acc[4][4];
#pragma unroll
    for (int i = 0; i < 4; i++)
#pragma unroll
        for (int j = 0; j < 4; j++) acc[i][j] = (f32x4){0.f, 0.f, 0.f, 0.f};

    for (int k0 = 0; k0 < DDIM; k0 += BK) {
#pragma unroll
        for (int i = 0; i < 4; i++) {
            gload_lds16(pa[i] + k0, &Asm[(tid + i * 256) * 8]);
            gload_lds16(pb[i] + k0, &Bsm[(tid + i * 256) * 8]);
        }
        __syncthreads();
#pragma unroll
        for (int s = 0; s < 2; s++) {
            const int cs = (((s << 2) + q) ^ (m16 & 7)) << 3;
            bf16x8 af[4], bfr[4];
#pragma unroll
            for (int i = 0; i < 4; i++)
                af[i] = *(const bf16x8*)&Asm[(wrow + i * 16 + m16) * BK + cs];
#pragma unroll
            for (int j = 0; j < 4; j++)
                bfr[j] = *(const bf16x8*)&Bsm[(wcol + j * 16 + m16) * BK + cs];
#pragma unroll
            for (int i = 0; i < 4; i++)
#pragma unroll
                for (int j = 0; j < 4; j++)
                    acc[i][j] = __builtin_amdgcn_mfma_f32_16x16x32_bf16(
                        af[i], bfr[j], acc[i][j], 0, 0, 0);
        }
        __syncthreads();
    }

    float bev[4];
#pragma unroll
    for (int j = 0; j < 4; j++) bev[j] = be[e * DDIM + nb * 128 + wcol + j * 16 + m16];
#pragma unroll
    for (int i = 0; i < 4; i++)
#pragma unroll
        for (int r = 0; r < 4; r++) {
            const int t = rs[wrow + i * 16 + q * 4 + r];
            if (t < 0) continue;
            const float pv = p[t];
#pragma unroll
            for (int j = 0; j < 4; j++) {
                const int n = nb * 128 + wcol + j * 16 + m16;
                float v = acc[i][j][r] + bev[j];
                v = v > 0.f ? v : 0.f;
                out[(size_t)t * DDIM + n] = v * pv;
            }
        }
}

// ---------------------------------------------------------------------------
extern "C" void kernel_launch(void* const* d_in, const int* in_sizes, int n_in,
                              void* d_out, int out_size, void* d_ws, size_t ws_size,
                              hipStream_t stream)
{
    const float* x  = (const float*)d_in[0];
    const float* Wg = (const float*)d_in[1];
    const float* bg = (const float*)d_in[2];
    const float* We = (const float*)d_in[3];
    const float* be = (const float*)d_in[4];
    float* out = (float*)d_out;

    char* ws = (char*)d_ws;
    float* logits = (float*)ws;                 ws += (size_t)TOK * DDIM * 4;
    unsigned short* WeT = (unsigned short*)ws;  ws += (size_t)NEXP * DDIM * DDIM * 2;
    unsigned short* WgT = (unsigned short*)ws;  ws += (size_t)DDIM * DDIM * 2;
    float* WgTf = (float*)ws;                   ws += (size_t)DDIM * DDIM * 4;
    unsigned short* xbf = (unsigned short*)ws;  ws += (size_t)TOK * DDIM * 2;
    float* p = (float*)ws;                      ws += (size_t)TOK * 4;
    int* e_arr = (int*)ws;                      ws += (size_t)TOK * 4;
    float* rmax_a = (float*)ws;                 ws += (size_t)TOK * 4;
    float* s_a = (float*)ws;                    ws += (size_t)TOK * 4;
    int* row_of_slot = (int*)ws;                ws += (size_t)RB_MAX * BMT * 4;
    int* cnt = (int*)ws;                        ws += NEXP * 4;
    int* cursor = (int*)ws;                     ws += NEXP * 4;
    int* ambig = (int*)ws;                      ws += AMBIG_CAP * 4;
    int* n_ambig = (int*)ws;                    ws += 4;

    cvt_x_init<<<TOK * DDIM / (256 * 8), 256, 0, stream>>>(
        x, xbf, cnt, cursor, n_ambig, row_of_slot);
    transpose_wg<<<dim3(32, 32), dim3(32, 8), 0, stream>>>(Wg, WgT, WgTf);
    transpose_mat<<<dim3(32, 32, NEXP), dim3(32, 8), 0, stream>>>(We, WeT);
    gating_mfma<<<1024, 256, 0, stream>>>(xbf, WgT, bg, logits);
    row_stats<<<TOK / 4, 256, 0, stream>>>(logits, p, e_arr, rmax_a, s_a, ambig, n_ambig);
    fixup<<<AMBIG_CAP, 64, 0, stream>>>(logits, x, WgTf, bg, rmax_a, s_a, ambig, n_ambig, e_arr, p);
    histo<<<TOK / 256, 256, 0, stream>>>(e_arr, cnt);
    assign_slots<<<TOK / 256, 256, 0, stream>>>(e_arr, cnt, cursor, row_of_slot);
    expert_gemm<<<1088, 256, 0, stream>>>(
        xbf, WeT, be, p, row_of_slot, cnt, out);
}